// Round 5
// baseline (136.262 us; speedup 1.0000x reference)
//
#include <hip/hip_runtime.h>
#include <hip/hip_bf16.h>

#define B_  4
#define S_  8192
#define H_  256
#define C_  128
#define NC_ 64
#define M_  (B_*S_)

typedef unsigned short u16;
typedef __attribute__((ext_vector_type(8))) short short8;
typedef __attribute__((ext_vector_type(4))) float f32x4;
typedef __attribute__((address_space(1))) void gas_t;
typedef __attribute__((address_space(3))) void las_t;

static constexpr float LNG   = -0.031748698f;          // ln(0.96875)
static constexpr float ROPE2 = -0.103810253f;          // -(2/256)*log2(10000)

__device__ __forceinline__ u16 f2b(float x) {
  union { __hip_bfloat16 b; u16 u; } c; c.b = __float2bfloat16(x); return c.u;
}
__device__ __forceinline__ float b2f(u16 u) {
  union { u16 u; __hip_bfloat16 b; } c; c.u = u; return __bfloat162float(c.b);
}
__device__ __forceinline__ f32x4 mfma16(short8 a, short8 b, f32x4 c) {
  return __builtin_amdgcn_mfma_f32_16x16x32_bf16(a, b, c, 0, 0, 0);
}

// ---- swizzled [128 rows][64 cols] bf16 tile; phys 16B-slot = slot ^ (row&7) ----
__device__ __forceinline__ void stageB(const u16* __restrict__ src, int stride,
                                       u16* lds, int t) {
  #pragma unroll
  for (int it = 0; it < 4; ++it) {
    const int u = it*256 + t, row = u >> 3, sl = u & 7, lsl = sl ^ (row & 7);
    uint4 v = *reinterpret_cast<const uint4*>(src + (size_t)row*stride + lsl*8);
    *reinterpret_cast<uint4*>(lds + u*8) = v;
  }
}
// f32 source, reg-staged convert, linear LDS dest w/ pre-swizzled source cols
__device__ __forceinline__ void stageF(const float* __restrict__ src, int stride,
                                       u16* lds, int t) {
  #pragma unroll
  for (int it = 0; it < 4; ++it) {
    const int u = it*256 + t, row = u >> 3, sl = u & 7, lsl = sl ^ (row & 7);
    const float* p = src + (size_t)row*stride + lsl*8;
    float4 a = *reinterpret_cast<const float4*>(p);
    float4 b = *reinterpret_cast<const float4*>(p + 4);
    u16 o[8] = {f2b(a.x), f2b(a.y), f2b(a.z), f2b(a.w),
                f2b(b.x), f2b(b.y), f2b(b.z), f2b(b.w)};
    *reinterpret_cast<uint4*>(lds + u*8) = *reinterpret_cast<uint4*>(o);
  }
}
// async direct-to-LDS, pre-swizzled global source, linear LDS dest
__device__ __forceinline__ void stageA(const u16* __restrict__ src, int stride,
                                       u16* smbase, int off, int t) {
  #pragma unroll
  for (int it = 0; it < 4; ++it) {
    const int u = it*256 + t, row = u >> 3, lsl = (u & 7) ^ (row & 7);
    const u16* gp = src + (size_t)row*stride + lsl*8;
    u16* lp = smbase + off + it*2048 + (t & 192)*8;   // wave-uniform base
    __builtin_amdgcn_global_load_lds((gas_t*)gp, (las_t*)lp, 16, 0, 0);
  }
}
__device__ __forceinline__ short8 fragr(const u16* lds, int row, int slot) {
  return *reinterpret_cast<const short8*>(lds + row*64 + ((slot ^ (row & 7)) << 3));
}

// ---------------- K0: prep — W -> transposed bf16, RoPE cos/sin table ----------------
__global__ __launch_bounds__(256) void prep(
    const float* __restrict__ Wq, const float* __restrict__ Wk,
    const float* __restrict__ Wv, u16* __restrict__ WhT,
    float* __restrict__ RTab)
{
  const int bid = blockIdx.x;
  if (bid < 96) {   // W transpose: 24576 threads, 8 elems each
    const int i = bid*256 + threadIdx.x;
    const int z = i >> 13, r = i & 8191;
    const int n = r >> 5, k0 = (r & 31) << 3;
    const float* W = (z == 0) ? Wq : (z == 1) ? Wk : Wv;
    u16 o[8];
    #pragma unroll
    for (int j = 0; j < 8; ++j) o[j] = f2b(W[(size_t)(k0 + j)*H_ + n]);
    *reinterpret_cast<uint4*>(WhT + ((size_t)z << 16) + n*H_ + k0) =
        *reinterpret_cast<uint4*>(o);
    return;
  }
  // RoPE table: idx over S_ x 128 pairs; RTab[(s*128+h)*2] = {cos, sin}
  const int i = (bid - 96)*256 + threadIdx.x;    // 0..1048575
  const int s = i >> 7, h = i & 127;
  const float invf = exp2f(ROPE2 * (float)h);
  float sn, cs;
  sincosf((float)s * invf, &sn, &cs);
  float2 o2 = make_float2(cs, sn);
  *reinterpret_cast<float2*>(RTab + 2*((size_t)s*128 + h)) = o2;
}

// ---------------- K1: fused QKV projection + RoPE + transposes ----------------
// z=0: Qh row-major (swapped mfma). z=1: Kh row-major + KT[b][d][s] (swapped mfma).
// z=2: VT[b][j][s] + VTw decay-weighted (normal mfma).
__global__ __launch_bounds__(256) void gemm_qkv(
    const float* __restrict__ X, const u16* __restrict__ WhT,
    const float* __restrict__ RTab,
    u16* __restrict__ Qh, u16* __restrict__ Kh,
    u16* __restrict__ KT, u16* __restrict__ VT, u16* __restrict__ VTw)
{
  __shared__ u16 SM[32768];   // 64KB: dbuf {A0,B0,A1,B1}x16KB; epilogue reuses regions
  const int t = threadIdx.x, l = t & 63, wid = t >> 6;
  const int wr = wid >> 1, wc = wid & 1, g = l >> 4, l15 = l & 15;
  const int z = blockIdx.z;
  const int row0 = blockIdx.x * 128, col0 = blockIdx.y * 128;
  const float* Asrc = X + (size_t)row0*H_;
  const u16* Bsrc = WhT + ((size_t)z << 16) + (size_t)col0*H_;
  f32x4 acc[4][4] = {};

  stageF(Asrc, H_, SM, t);
  stageA(Bsrc, H_, SM, 8192, t);
  __syncthreads();
  for (int ks = 0; ks < 4; ++ks) {
    const int cur = (ks & 1) * 16384;
    if (ks < 3) {
      stageF(Asrc + (ks+1)*64, H_, SM + (16384 - cur), t);
      stageA(Bsrc + (ks+1)*64, H_, SM, 16384 - cur + 8192, t);
    }
    const u16* As = SM + cur;
    const u16* Bs = SM + cur + 8192;
    #pragma unroll
    for (int kb = 0; kb < 2; ++kb) {
      short8 a[4], b[4];
      #pragma unroll
      for (int i = 0; i < 4; ++i) a[i] = fragr(As, wr*64 + i*16 + l15, kb*4 + g);
      #pragma unroll
      for (int j = 0; j < 4; ++j) b[j] = fragr(Bs, wc*64 + j*16 + l15, kb*4 + g);
      if (z < 2) {
        #pragma unroll
        for (int i = 0; i < 4; ++i)
          #pragma unroll
          for (int j = 0; j < 4; ++j)
            acc[i][j] = mfma16(b[j], a[i], acc[i][j]);   // swapped: l15=m, regs=n
      } else {
        #pragma unroll
        for (int i = 0; i < 4; ++i)
          #pragma unroll
          for (int j = 0; j < 4; ++j)
            acc[i][j] = mfma16(a[i], b[j], acc[i][j]);
      }
    }
    __syncthreads();
  }

  if (z < 2) {
    // ---- RoPE fully in-lane via table: lane holds (m, n0..n0+3) = 2 pairs ----
    const float4* RT4 = reinterpret_cast<const float4*>(RTab);
    #pragma unroll
    for (int i = 0; i < 4; ++i) {
      const int s = (row0 + wr*64 + i*16 + l15) & (S_-1);
      #pragma unroll
      for (int j = 0; j < 4; ++j) {
        const int ng = col0 + wc*64 + j*16 + g*4;
        const float4 tb = RT4[(size_t)s*64 + (ng >> 2)];   // {cs0,sn0,cs1,sn1}
        const float x0 = acc[i][j][0], x1 = acc[i][j][1];
        const float x2 = acc[i][j][2], x3 = acc[i][j][3];
        acc[i][j][0] = x0*tb.x - x1*tb.y;  acc[i][j][1] = x1*tb.x + x0*tb.y;
        acc[i][j][2] = x2*tb.z - x3*tb.w;  acc[i][j][3] = x3*tb.z + x2*tb.w;
      }
    }
    // ---- row-major restage: SM[128 m][128 n] u16, 8B-granule swizzle ----
    #pragma unroll
    for (int i = 0; i < 4; ++i) {
      const int m = wr*64 + i*16 + l15;
      #pragma unroll
      for (int j = 0; j < 4; ++j) {
        const int n0 = wc*64 + j*16 + g*4;
        ushort4 pk;
        pk.x = f2b(acc[i][j][0]); pk.y = f2b(acc[i][j][1]);
        pk.z = f2b(acc[i][j][2]); pk.w = f2b(acc[i][j][3]);
        *reinterpret_cast<ushort4*>(SM + m*128 + ((((n0 >> 2) ^ ((m & 7) << 2))) << 2)) = pk;
      }
    }
    __syncthreads();
    u16* Ob = (z == 0) ? Qh : Kh;
    #pragma unroll
    for (int it = 0; it < 8; ++it) {
      const int u = it*256 + t;
      const int row = u >> 4, sl = u & 15;
      uint4 v = *reinterpret_cast<const uint4*>(
          SM + row*128 + ((((sl << 1) ^ ((row & 7) << 2))) << 2));
      *reinterpret_cast<uint4*>(Ob + (size_t)(row0 + row)*H_ + col0 + sl*8) = v;
    }
  }

  if (z == 1) {
    // ---- transpose restage: SM[128 d][128 s] u16, 8-granule swizzle ----
    __syncthreads();
    #pragma unroll
    for (int i = 0; i < 4; ++i) {
      const int m = wr*64 + i*16 + l15;          // s
      #pragma unroll
      for (int j = 0; j < 4; ++j) {
        #pragma unroll
        for (int r = 0; r < 4; ++r) {
          const int n = wc*64 + j*16 + g*4 + r;  // d
          SM[n*128 + ((((m >> 3) ^ (n & 7)) << 3) + (m & 7))] = f2b(acc[i][j][r]);
        }
      }
    }
    __syncthreads();
    #pragma unroll
    for (int it = 0; it < 8; ++it) {
      const int u = it*256 + t;
      const int d = u >> 4, sl = u & 15;
      uint4 v = *reinterpret_cast<const uint4*>(SM + d*128 + ((sl ^ (d & 7)) << 3));
      const int rg0 = row0 + sl*8;
      const int bb = rg0 >> 13, s0 = rg0 & (S_-1);
      *reinterpret_cast<uint4*>(KT + (((size_t)(bb*H_ + col0 + d)) << 13) + s0) = v;
    }
  }

  if (z == 2) {
    // decay table gamma^k in LDS (after dbuf regions)
    float* gpT = reinterpret_cast<float*>(SM + 16384);
    if (t < 128) gpT[t] = expf((float)t * LNG);
    // ---- per-wave 64x64 transpose regions (natural frag pack along s) ----
    #pragma unroll
    for (int jb = 0; jb < 4; ++jb) {
      const int cl = jb*16 + l15;                // j (V output col)
      #pragma unroll
      for (int ib = 0; ib < 4; ++ib) {
        const int rl0 = ib*16 + g*4;             // s local
        u16* R = SM + wid*4096;
        ushort4 pk;
        pk.x = f2b(acc[ib][jb][0]); pk.y = f2b(acc[ib][jb][1]);
        pk.z = f2b(acc[ib][jb][2]); pk.w = f2b(acc[ib][jb][3]);
        *reinterpret_cast<ushort4*>(R + cl*64 + (rl0 ^ ((cl & 7) << 3))) = pk;
      }
    }
    __syncthreads();
    #pragma unroll
    for (int it = 0; it < 8; ++it) {
      const int u = it*256 + t;
      const int w = u >> 9, cl = (u >> 3) & 63, sl = u & 7;
      const int sp = sl ^ (cl & 7);
      uint4 v = *reinterpret_cast<const uint4*>(SM + w*4096 + cl*64 + sp*8);
      const int dg  = col0 + (w & 1)*64 + cl;
      const int rg0 = row0 + ((w >> 1))*64 + sl*8;
      const int bb = rg0 >> 13, s0 = rg0 & (S_-1);
      const size_t dst = ((size_t)(bb*H_ + dg) << 13) + s0;
      *reinterpret_cast<uint4*>(VT + dst) = v;
      const u16* pv = reinterpret_cast<const u16*>(&v);
      u16 ow[8];
      const int k0 = C_ - 1 - (s0 & (C_-1));     // in [7,127], k0-j2 >= 0
      #pragma unroll
      for (int j2 = 0; j2 < 8; ++j2) ow[j2] = f2b(b2f(pv[j2]) * gpT[k0 - j2]);
      *reinterpret_cast<uint4*>(VTw + dst) = *reinterpret_cast<uint4*>(ow);
    }
  }
}

// ---------------- K2: chunk outer product Tt[b,c][j][i] = sum_m w(m) V[m][j] K[m][i] ----
__global__ __launch_bounds__(256) void chunk_outer(
    const u16* __restrict__ KT, const u16* __restrict__ VTw, u16* __restrict__ Tt)
{
  __shared__ u16 SM[32768];   // 64KB dbuf; epilogue reuses [0,16384)
  const int t = threadIdx.x, l = t & 63, wid = t >> 6;
  const int wr = wid >> 1, wc = wid & 1, g = l >> 4, l15 = l & 15;
  const int c = blockIdx.x, b = blockIdx.y, q = blockIdx.z;
  const int j0 = (q >> 1) * 128, i0 = (q & 1) * 128;
  const u16* Asrc = VTw + ((size_t)(b*H_ + j0) << 13) + c*C_;
  const u16* Bsrc = KT  + ((size_t)(b*H_ + i0) << 13) + c*C_;
  f32x4 acc[4][4] = {};

  stageA(Asrc, S_, SM, 0, t);
  stageA(Bsrc, S_, SM, 8192, t);
  __syncthreads();
  for (int ks = 0; ks < 2; ++ks) {
    const int cur = (ks & 1) * 16384;
    if (ks < 1) {
      stageA(Asrc + 64, S_, SM, 16384, t);
      stageA(Bsrc + 64, S_, SM, 16384 + 8192, t);
    }
    const u16* As = SM + cur;
    const u16* Bs = SM + cur + 8192;
    #pragma unroll
    for (int kb = 0; kb < 2; ++kb) {
      short8 a[4], bb[4];
      #pragma unroll
      for (int i = 0; i < 4; ++i) a[i] = fragr(As, wr*64 + i*16 + l15, kb*4 + g);
      #pragma unroll
      for (int j = 0; j < 4; ++j) bb[j] = fragr(Bs, wc*64 + j*16 + l15, kb*4 + g);
      #pragma unroll
      for (int i = 0; i < 4; ++i)
        #pragma unroll
        for (int j = 0; j < 4; ++j)
          acc[i][j] = mfma16(a[i], bb[j], acc[i][j]);
    }
    __syncthreads();
  }
  // restage [128 j][128 i] u16 with 8-granule swizzle, coalesced store
  #pragma unroll
  for (int jb = 0; jb < 4; ++jb) {
    const int il = wc*64 + jb*16 + l15;
    #pragma unroll
    for (int ib = 0; ib < 4; ++ib) {
      #pragma unroll
      for (int r = 0; r < 4; ++r) {
        const int jl = wr*64 + ib*16 + g*4 + r;
        SM[jl*128 + ((((il >> 3) ^ (jl & 7)) << 3) + (il & 7))] = f2b(acc[ib][jb][r]);
      }
    }
  }
  __syncthreads();
  const size_t tb = ((size_t)(b*NC_ + c)) << 16;
  #pragma unroll
  for (int it = 0; it < 8; ++it) {
    const int u = it*256 + t;
    const int jl = u >> 4, sl = u & 15;
    uint4 v = *reinterpret_cast<const uint4*>(SM + jl*128 + ((sl ^ (jl & 7)) << 3));
    *reinterpret_cast<uint4*>(Tt + tb + (size_t)(j0 + jl)*H_ + i0 + sl*8) = v;
  }
}

// ---------------- K3: in-place exclusive scan: state[c] = g^C state[c-1] + T[c-1] ----
// 2 elems/thread + 1-chunk prefetch to break the latency chain
__global__ __launch_bounds__(256) void scan_state(u16* __restrict__ Tt)
{
  const unsigned e = blockIdx.x*256u + threadIdx.x;   // B_*32768 threads
  const unsigned b = e >> 15, el = (e & 32767u) << 1;
  const float gC = expf((float)C_ * LNG);
  float r0 = 0.f, r1 = 0.f;
  size_t p = (((size_t)b * NC_) << 16) + el;
  unsigned v = *reinterpret_cast<unsigned*>(Tt + p);
  for (int c = 0; c < NC_; ++c, p += 65536) {
    unsigned vn = 0;
    if (c < NC_-1) vn = *reinterpret_cast<unsigned*>(Tt + p + 65536);
    *reinterpret_cast<unsigned*>(Tt + p) =
        (unsigned)f2b(r0) | ((unsigned)f2b(r1) << 16);
    r0 = fmaf(gC, r0, b2f((u16)(v & 0xffff)));
    r1 = fmaf(gC, r1, b2f((u16)(v >> 16)));
    v = vn;
  }
}

// ---------------- K4: per-chunk output via MFMA ----------------
__global__ __launch_bounds__(256) void retention_out(
    const u16* __restrict__ Qh, const u16* __restrict__ Kh,
    const u16* __restrict__ VT, const u16* __restrict__ Tt,
    float* __restrict__ Out)
{
  __shared__ u16 SM[33024];   // 64.5KB: Sc | StA | StB | gpT table (last 512B)
  const int t = threadIdx.x, l = t & 63, wid = t >> 6;
  const int g = l >> 4, l15 = l & 15;
  const int c = blockIdx.x, b = blockIdx.y;
  u16* Sc = SM; u16* StA = SM + 16384; u16* StB = SM + 24576;
  float* gpT = reinterpret_cast<float*>(SM + 32768);
  if (t < 132) gpT[t] = expf((float)t * LNG);
  const size_t chunkrow = ((size_t)(b*S_ + c*C_)) << 8;   // * H_

  // ---- phase 1: St[m][n] = sum_d K[m,d] Q[n,d]; mask+decay -> Sc[n][m] (swizzled) ----
  {
    const int m0w = (wid >> 1)*64, n0w = (wid & 1)*64;
    f32x4 acc[4][4] = {};
    for (int ks = 0; ks < 4; ++ks) {
      stageB(Kh + chunkrow + ks*64, H_, StA, t);
      stageB(Qh + chunkrow + ks*64, H_, StB, t);
      __syncthreads();
      #pragma unroll
      for (int kb = 0; kb < 2; ++kb) {
        short8 a[4], bb[4];
        #pragma unroll
        for (int i = 0; i < 4; ++i) a[i] = fragr(StA, m0w + i*16 + l15, kb*4 + g);
        #pragma unroll
        for (int j = 0; j < 4; ++j) bb[j] = fragr(StB, n0w + j*16 + l15, kb*4 + g);
        #pragma unroll
        for (int i = 0; i < 4; ++i)
          #pragma unroll
          for (int j = 0; j < 4; ++j)
            acc[i][j] = mfma16(a[i], bb[j], acc[i][j]);
      }
      __syncthreads();
    }
    #pragma unroll
    for (int jb = 0; jb < 4; ++jb) {
      const int n = n0w + jb*16 + l15;
      #pragma unroll
      for (int ib = 0; ib < 4; ++ib) {
        const int m0 = m0w + ib*16 + g*4;
        ushort4 pk;
        #pragma unroll
        for (int r = 0; r < 4; ++r) {
          const int m = m0 + r;
          const float sv = (n >= m) ? acc[ib][jb][r] * gpT[n - m] : 0.f;
          reinterpret_cast<u16*>(&pk)[r] = f2b(sv);
        }
        *reinterpret_cast<ushort4*>(Sc + n*128 + (m0 ^ ((n & 15) << 3))) = pk;
      }
    }
  }
  __syncthreads();

  // ---- phase 2: D[j][n] = gamma^(n+1) * (Q @ state)^T + (S V)^T ----
  const int j0w = (wid >> 1)*64, n0w = (wid & 1)*64;
  const size_t sbase = ((size_t)(b*NC_ + c)) << 16;
  for (int h = 0; h < 2; ++h) {
    const int j0 = h*128;
    f32x4 acc[4][4] = {};
    // cross: contraction over d (4 ksteps)
    for (int ks = 0; ks < 4; ++ks) {
      stageB(Tt + sbase + (size_t)j0*H_ + ks*64, H_, StA, t);
      stageB(Qh + chunkrow + ks*64, H_, StB, t);
      __syncthreads();
      #pragma unroll
      for (int kb = 0; kb < 2; ++kb) {
        short8 a[4], bb[4];
        #pragma unroll
        for (int i = 0; i < 4; ++i) a[i] = fragr(StA, j0w + i*16 + l15, kb*4 + g);
        #pragma unroll
        for (int j = 0; j < 4; ++j) bb[j] = fragr(StB, n0w + j*16 + l15, kb*4 + g);
        #pragma unroll
        for (int i = 0; i < 4; ++i)
          #pragma unroll
          for (int j = 0; j < 4; ++j)
            acc[i][j] = mfma16(a[i], bb[j], acc[i][j]);
      }
      __syncthreads();
    }
    // scale cross by gamma^(n+1)
    #pragma unroll
    for (int jb = 0; jb < 4; ++jb) {
      const float gn = gpT[n0w + jb*16 + l15 + 1];
      #pragma unroll
      for (int ib = 0; ib < 4; ++ib)
        #pragma unroll
        for (int r = 0; r < 4; ++r) acc[ib][jb][r] *= gn;
    }
    // local: contraction over m (2 ksteps), B from Sc
    for (int ks2 = 0; ks2 < 2; ++ks2) {
      stageB(VT + ((size_t)(b*H_ + j0) << 13) + c*C_ + ks2*64, S_, StA, t);
      __syncthreads();
      #pragma unroll
      for (int kb = 0; kb < 2; ++kb) {
        short8 a[4], bb[4];
        #pragma unroll
        for (int i = 0; i < 4; ++i) a[i] = fragr(StA, j0w + i*16 + l15, kb*4 + g);
        #pragma unroll
        for (int j = 0; j < 4; ++j) {
          const int n = n0w + j*16 + l15;
          bb[j] = *reinterpret_cast<const short8*>(
              Sc + n*128 + (((ks2*8 + kb*4 + g) ^ (n & 15)) << 3));
        }
        #pragma unroll
        for (int i = 0; i < 4; ++i)
          #pragma unroll
          for (int j = 0; j < 4; ++j)
            acc[i][j] = mfma16(a[i], bb[j], acc[i][j]);
      }
      __syncthreads();
    }
    // epilogue: restage [64 n][128 j] f32 in LDS (swizzled), coalesced global store
    float* OL = reinterpret_cast<float*>(SM + 16384);   // 32KB region
    for (int ph = 0; ph < 2; ++ph) {
      if ((wid & 1) == ph) {
        #pragma unroll
        for (int jb = 0; jb < 4; ++jb) {
          const int nl = jb*16 + l15;
          #pragma unroll
          for (int ib = 0; ib < 4; ++ib) {
            const int jl = j0w + ib*16 + g*4;
            *reinterpret_cast<f32x4*>(OL + nl*128 + (jl ^ ((nl & 15) << 2))) = acc[ib][jb];
          }
        }
      }
      __syncthreads();
      #pragma unroll
      for (int it = 0; it < 8; ++it) {
        const int u = it*256 + t;
        const int nl = u >> 5, sl = u & 31;
        f32x4 v = *reinterpret_cast<const f32x4*>(OL + nl*128 + ((sl ^ (nl & 15)) << 2));
        const int n = c*C_ + ph*64 + nl;
        *reinterpret_cast<f32x4*>(Out + (((size_t)(b*S_ + n)) << 8) + j0 + sl*4) = v;
      }
      __syncthreads();
    }
  }
}

extern "C" void kernel_launch(void* const* d_in, const int* in_sizes, int n_in,
                              void* d_out, int out_size, void* d_ws, size_t ws_size,
                              hipStream_t stream) {
  const float* X  = (const float*)d_in[0];
  const float* Wq = (const float*)d_in[1];
  const float* Wk = (const float*)d_in[2];
  const float* Wv = (const float*)d_in[3];
  float* Out = (float*)d_out;
  u16* ws = (u16*)d_ws;
  // workspace (u16): WhT 196608 | RTab 4194304 | Qh,Kh,KT,VT,VTw 8388608 ea | Tt 16777216 (~126 MB)
  u16*   WhT  = ws;
  float* RTab = (float*)(ws + 196608);
  u16* Qh  = ws  + 196608 + 4194304;
  u16* Kh  = Qh  + (size_t)M_*H_;
  u16* KT  = Kh  + (size_t)M_*H_;
  u16* VT  = KT  + (size_t)M_*H_;
  u16* VTw = VT  + (size_t)M_*H_;
  u16* Tt  = VTw + (size_t)M_*H_;

  prep<<<96 + 4096, 256, 0, stream>>>(Wq, Wk, Wv, WhT, RTab);
  gemm_qkv<<<dim3(M_/128, H_/128, 3), 256, 0, stream>>>(X, WhT, RTab, Qh, Kh, KT, VT, VTw);
  chunk_outer<<<dim3(NC_, B_, 4), 256, 0, stream>>>(KT, VTw, Tt);
  scan_state<<<(B_*32768)/256, 256, 0, stream>>>(Tt);
  retention_out<<<dim3(NC_, B_), 256, 0, stream>>>(Qh, Kh, VT, Tt, Out);
}

// Round 6
// 112.805 us; speedup vs baseline: 1.2079x; 1.2079x over previous
//
#include <hip/hip_runtime.h>
#include <hip/hip_bf16.h>

#define B_  4
#define S_  8192
#define H_  256
#define C_  128
#define NC_ 64
#define M_  (B_*S_)

typedef unsigned short u16;
typedef __attribute__((ext_vector_type(8))) short short8;
typedef __attribute__((ext_vector_type(4))) float f32x4;
typedef __attribute__((address_space(1))) void gas_t;
typedef __attribute__((address_space(3))) void las_t;

static constexpr float LNG   = -0.031748698f;          // ln(0.96875)
static constexpr float L2G   = -0.045803690f;          // log2(0.96875)
static constexpr float ROPE2 = -0.103810253f;          // -(2/256)*log2(10000)

__device__ __forceinline__ u16 f2b(float x) {
  union { __hip_bfloat16 b; u16 u; } c; c.b = __float2bfloat16(x); return c.u;
}
__device__ __forceinline__ float b2f(u16 u) {
  union { u16 u; __hip_bfloat16 b; } c; c.u = u; return __bfloat162float(c.b);
}
__device__ __forceinline__ f32x4 mfma16(short8 a, short8 b, f32x4 c) {
  return __builtin_amdgcn_mfma_f32_16x16x32_bf16(a, b, c, 0, 0, 0);
}

// ---- swizzled [128 rows][64 cols] bf16 tile; phys 16B-slot = slot ^ (row&7) ----
// async direct-to-LDS: pre-swizzled global source, linear LDS dest
__device__ __forceinline__ void stageA(const u16* __restrict__ src, int stride,
                                       u16* smbase, int off, int t) {
  #pragma unroll
  for (int it = 0; it < 4; ++it) {
    const int u = it*256 + t, row = u >> 3, lsl = (u & 7) ^ (row & 7);
    const u16* gp = src + (size_t)row*stride + lsl*8;
    u16* lp = smbase + off + it*2048 + (t & 192)*8;   // wave-uniform base
    __builtin_amdgcn_global_load_lds((gas_t*)gp, (las_t*)lp, 16, 0, 0);
  }
}
__device__ __forceinline__ short8 fragr(const u16* lds, int row, int slot) {
  return *reinterpret_cast<const short8*>(lds + row*64 + ((slot ^ (row & 7)) << 3));
}

// ---------------- K0: prep — X->bf16, W->transposed bf16, RoPE table ----------------
__global__ __launch_bounds__(256) void prep(
    const float* __restrict__ X, const float* __restrict__ Wq,
    const float* __restrict__ Wk, const float* __restrict__ Wv,
    u16* __restrict__ Xh, u16* __restrict__ WhT, float* __restrict__ RTab)
{
  const int bid = blockIdx.x;
  if (bid < 96) {   // W transpose: 24576 threads, 8 elems each
    const int i = bid*256 + threadIdx.x;
    const int z = i >> 13, r = i & 8191;
    const int n = r >> 5, k0 = (r & 31) << 3;
    const float* W = (z == 0) ? Wq : (z == 1) ? Wk : Wv;
    u16 o[8];
    #pragma unroll
    for (int j = 0; j < 8; ++j) o[j] = f2b(W[(size_t)(k0 + j)*H_ + n]);
    *reinterpret_cast<uint4*>(WhT + ((size_t)z << 16) + n*H_ + k0) =
        *reinterpret_cast<uint4*>(o);
    return;
  }
  if (bid < 96 + 4096) {  // X -> bf16: 8 elems/thread
    const int j = (bid - 96)*256 + threadIdx.x;
    const float* p = X + (size_t)j*8;
    float4 a = *reinterpret_cast<const float4*>(p);
    float4 b = *reinterpret_cast<const float4*>(p + 4);
    u16 o[8] = {f2b(a.x), f2b(a.y), f2b(a.z), f2b(a.w),
                f2b(b.x), f2b(b.y), f2b(b.z), f2b(b.w)};
    *reinterpret_cast<uint4*>(Xh + (size_t)j*8) = *reinterpret_cast<uint4*>(o);
    return;
  }
  // RoPE table: RTab[(s*128+h)*2] = {cos, sin}
  const int i = (bid - 4192)*256 + threadIdx.x;    // 0..1048575
  const int s = i >> 7, h = i & 127;
  const float invf = exp2f(ROPE2 * (float)h);
  float sn, cs;
  sincosf((float)s * invf, &sn, &cs);
  *reinterpret_cast<float2*>(RTab + 2*((size_t)s*128 + h)) = make_float2(cs, sn);
}

// ---------------- K1: fused QKV projection + RoPE + transposes ----------------
// z=0: Qh row-major (swapped mfma). z=1: Kh row-major + KT[b][d][s] (swapped mfma).
// z=2: VT[b][j][s] + VTw decay-weighted (normal mfma).
__global__ __launch_bounds__(256) void gemm_qkv(
    const u16* __restrict__ Xh, const u16* __restrict__ WhT,
    const float* __restrict__ RTab,
    u16* __restrict__ Qh, u16* __restrict__ Kh,
    u16* __restrict__ KT, u16* __restrict__ VT, u16* __restrict__ VTw)
{
  __shared__ u16 SM[32768];   // 64KB: dbuf {A0,B0,A1,B1}x16KB; epilogue reuses regions
  const int t = threadIdx.x, l = t & 63, wid = t >> 6;
  const int wr = wid >> 1, wc = wid & 1, g = l >> 4, l15 = l & 15;
  const int z = blockIdx.z;
  const int row0 = blockIdx.x * 128, col0 = blockIdx.y * 128;
  const u16* Asrc = Xh + (size_t)row0*H_;
  const u16* Bsrc = WhT + ((size_t)z << 16) + (size_t)col0*H_;
  f32x4 acc[4][4] = {};

  stageA(Asrc, H_, SM, 0, t);
  stageA(Bsrc, H_, SM, 8192, t);
  __syncthreads();
  for (int ks = 0; ks < 4; ++ks) {
    const int cur = (ks & 1) * 16384;
    if (ks < 3) {
      stageA(Asrc + (ks+1)*64, H_, SM, 16384 - cur, t);
      stageA(Bsrc + (ks+1)*64, H_, SM, 16384 - cur + 8192, t);
    }
    const u16* As = SM + cur;
    const u16* Bs = SM + cur + 8192;
    #pragma unroll
    for (int kb = 0; kb < 2; ++kb) {
      short8 a[4], b[4];
      #pragma unroll
      for (int i = 0; i < 4; ++i) a[i] = fragr(As, wr*64 + i*16 + l15, kb*4 + g);
      #pragma unroll
      for (int j = 0; j < 4; ++j) b[j] = fragr(Bs, wc*64 + j*16 + l15, kb*4 + g);
      if (z < 2) {
        #pragma unroll
        for (int i = 0; i < 4; ++i)
          #pragma unroll
          for (int j = 0; j < 4; ++j)
            acc[i][j] = mfma16(b[j], a[i], acc[i][j]);   // swapped: l15=m, regs=n
      } else {
        #pragma unroll
        for (int i = 0; i < 4; ++i)
          #pragma unroll
          for (int j = 0; j < 4; ++j)
            acc[i][j] = mfma16(a[i], b[j], acc[i][j]);
      }
    }
    __syncthreads();
  }

  if (z < 2) {
    // ---- RoPE fully in-lane via table: lane holds (m, n0..n0+3) = 2 pairs ----
    const float4* RT4 = reinterpret_cast<const float4*>(RTab);
    #pragma unroll
    for (int i = 0; i < 4; ++i) {
      const int s = (row0 + wr*64 + i*16 + l15) & (S_-1);
      #pragma unroll
      for (int j = 0; j < 4; ++j) {
        const int ng = col0 + wc*64 + j*16 + g*4;
        const float4 tb = RT4[(size_t)s*64 + (ng >> 2)];   // {cs0,sn0,cs1,sn1}
        const float x0 = acc[i][j][0], x1 = acc[i][j][1];
        const float x2 = acc[i][j][2], x3 = acc[i][j][3];
        acc[i][j][0] = x0*tb.x - x1*tb.y;  acc[i][j][1] = x1*tb.x + x0*tb.y;
        acc[i][j][2] = x2*tb.z - x3*tb.w;  acc[i][j][3] = x3*tb.z + x2*tb.w;
      }
    }
    // ---- row-major restage: SM[128 m][128 n] u16, 8B-granule swizzle ----
    #pragma unroll
    for (int i = 0; i < 4; ++i) {
      const int m = wr*64 + i*16 + l15;
      #pragma unroll
      for (int j = 0; j < 4; ++j) {
        const int n0 = wc*64 + j*16 + g*4;
        ushort4 pk;
        pk.x = f2b(acc[i][j][0]); pk.y = f2b(acc[i][j][1]);
        pk.z = f2b(acc[i][j][2]); pk.w = f2b(acc[i][j][3]);
        *reinterpret_cast<ushort4*>(SM + m*128 + ((((n0 >> 2) ^ ((m & 7) << 2))) << 2)) = pk;
      }
    }
    __syncthreads();
    u16* Ob = (z == 0) ? Qh : Kh;
    #pragma unroll
    for (int it = 0; it < 8; ++it) {
      const int u = it*256 + t;
      const int row = u >> 4, sl = u & 15;
      uint4 v = *reinterpret_cast<const uint4*>(
          SM + row*128 + ((((sl << 1) ^ ((row & 7) << 2))) << 2));
      *reinterpret_cast<uint4*>(Ob + (size_t)(row0 + row)*H_ + col0 + sl*8) = v;
    }
  }

  if (z == 1) {
    // ---- transpose restage: SM[128 d][128 s] u16, 8-granule swizzle ----
    __syncthreads();
    #pragma unroll
    for (int i = 0; i < 4; ++i) {
      const int m = wr*64 + i*16 + l15;          // s
      #pragma unroll
      for (int j = 0; j < 4; ++j) {
        #pragma unroll
        for (int r = 0; r < 4; ++r) {
          const int n = wc*64 + j*16 + g*4 + r;  // d
          SM[n*128 + ((((m >> 3) ^ (n & 7)) << 3) + (m & 7))] = f2b(acc[i][j][r]);
        }
      }
    }
    __syncthreads();
    #pragma unroll
    for (int it = 0; it < 8; ++it) {
      const int u = it*256 + t;
      const int d = u >> 4, sl = u & 15;
      uint4 v = *reinterpret_cast<const uint4*>(SM + d*128 + ((sl ^ (d & 7)) << 3));
      const int rg0 = row0 + sl*8;
      const int bb = rg0 >> 13, s0 = rg0 & (S_-1);
      *reinterpret_cast<uint4*>(KT + (((size_t)(bb*H_ + col0 + d)) << 13) + s0) = v;
    }
  }

  if (z == 2) {
    // ---- per-wave 64x64 transpose regions (natural frag pack along s) ----
    #pragma unroll
    for (int jb = 0; jb < 4; ++jb) {
      const int cl = jb*16 + l15;                // j (V output col)
      #pragma unroll
      for (int ib = 0; ib < 4; ++ib) {
        const int rl0 = ib*16 + g*4;             // s local
        u16* R = SM + wid*4096;
        ushort4 pk;
        pk.x = f2b(acc[ib][jb][0]); pk.y = f2b(acc[ib][jb][1]);
        pk.z = f2b(acc[ib][jb][2]); pk.w = f2b(acc[ib][jb][3]);
        *reinterpret_cast<ushort4*>(R + cl*64 + (rl0 ^ ((cl & 7) << 3))) = pk;
      }
    }
    __syncthreads();
    #pragma unroll
    for (int it = 0; it < 8; ++it) {
      const int u = it*256 + t;
      const int w = u >> 9, cl = (u >> 3) & 63, sl = u & 7;
      const int sp = sl ^ (cl & 7);
      uint4 v = *reinterpret_cast<const uint4*>(SM + w*4096 + cl*64 + sp*8);
      const int dg  = col0 + (w & 1)*64 + cl;
      const int rg0 = row0 + ((w >> 1))*64 + sl*8;
      const int bb = rg0 >> 13, s0 = rg0 & (S_-1);
      const size_t dst = ((size_t)(bb*H_ + dg) << 13) + s0;
      *reinterpret_cast<uint4*>(VT + dst) = v;
      const u16* pv = reinterpret_cast<const u16*>(&v);
      u16 ow[8];
      const int k0 = C_ - 1 - (s0 & (C_-1));     // >= 7
      #pragma unroll
      for (int j2 = 0; j2 < 8; ++j2)
        ow[j2] = f2b(b2f(pv[j2]) * exp2f((float)(k0 - j2) * L2G));
      *reinterpret_cast<uint4*>(VTw + dst) = *reinterpret_cast<uint4*>(ow);
    }
  }
}

// ---------------- K2: chunk outer product Tt[b,c][j][i] = sum_m w(m) V[m][j] K[m][i] ----
__global__ __launch_bounds__(256) void chunk_outer(
    const u16* __restrict__ KT, const u16* __restrict__ VTw, u16* __restrict__ Tt)
{
  __shared__ u16 SM[32768];   // 64KB dbuf; epilogue reuses [0,16384)
  const int t = threadIdx.x, l = t & 63, wid = t >> 6;
  const int wr = wid >> 1, wc = wid & 1, g = l >> 4, l15 = l & 15;
  const int c = blockIdx.x, b = blockIdx.y, q = blockIdx.z;
  const int j0 = (q >> 1) * 128, i0 = (q & 1) * 128;
  const u16* Asrc = VTw + ((size_t)(b*H_ + j0) << 13) + c*C_;
  const u16* Bsrc = KT  + ((size_t)(b*H_ + i0) << 13) + c*C_;
  f32x4 acc[4][4] = {};

  stageA(Asrc, S_, SM, 0, t);
  stageA(Bsrc, S_, SM, 8192, t);
  __syncthreads();
  for (int ks = 0; ks < 2; ++ks) {
    const int cur = (ks & 1) * 16384;
    if (ks < 1) {
      stageA(Asrc + 64, S_, SM, 16384, t);
      stageA(Bsrc + 64, S_, SM, 16384 + 8192, t);
    }
    const u16* As = SM + cur;
    const u16* Bs = SM + cur + 8192;
    #pragma unroll
    for (int kb = 0; kb < 2; ++kb) {
      short8 a[4], bb[4];
      #pragma unroll
      for (int i = 0; i < 4; ++i) a[i] = fragr(As, wr*64 + i*16 + l15, kb*4 + g);
      #pragma unroll
      for (int j = 0; j < 4; ++j) bb[j] = fragr(Bs, wc*64 + j*16 + l15, kb*4 + g);
      #pragma unroll
      for (int i = 0; i < 4; ++i)
        #pragma unroll
        for (int j = 0; j < 4; ++j)
          acc[i][j] = mfma16(a[i], bb[j], acc[i][j]);
    }
    __syncthreads();
  }
  // restage [128 j][128 i] u16 with 8-granule swizzle, coalesced store
  #pragma unroll
  for (int jb = 0; jb < 4; ++jb) {
    const int il = wc*64 + jb*16 + l15;
    #pragma unroll
    for (int ib = 0; ib < 4; ++ib) {
      #pragma unroll
      for (int r = 0; r < 4; ++r) {
        const int jl = wr*64 + ib*16 + g*4 + r;
        SM[jl*128 + ((((il >> 3) ^ (jl & 7)) << 3) + (il & 7))] = f2b(acc[ib][jb][r]);
      }
    }
  }
  __syncthreads();
  const size_t tb = ((size_t)(b*NC_ + c)) << 16;
  #pragma unroll
  for (int it = 0; it < 8; ++it) {
    const int u = it*256 + t;
    const int jl = u >> 4, sl = u & 15;
    uint4 v = *reinterpret_cast<const uint4*>(SM + jl*128 + ((sl ^ (jl & 7)) << 3));
    *reinterpret_cast<uint4*>(Tt + tb + (size_t)(j0 + jl)*H_ + i0 + sl*8) = v;
  }
}

// ---------------- K3: exclusive scan with 16-deep batched prefetch ----------------
__global__ __launch_bounds__(256) void scan_state(u16* __restrict__ Tt)
{
  const unsigned e = blockIdx.x*256u + threadIdx.x;   // B_*32768 threads, 2 elems each
  const unsigned b = e >> 15, el = (e & 32767u) << 1;
  const float gC = exp2f(128.0f * L2G);
  float r0 = 0.f, r1 = 0.f;
  const size_t base = (((size_t)b * NC_) << 16) + el;
  #pragma unroll
  for (int grp = 0; grp < 4; ++grp) {
    unsigned buf[16];
    #pragma unroll
    for (int i2 = 0; i2 < 16; ++i2)
      buf[i2] = *reinterpret_cast<const unsigned*>(Tt + base + (size_t)(grp*16 + i2)*65536);
    #pragma unroll
    for (int i2 = 0; i2 < 16; ++i2) {
      const unsigned v = buf[i2];
      *reinterpret_cast<unsigned*>(Tt + base + (size_t)(grp*16 + i2)*65536) =
          (unsigned)f2b(r0) | ((unsigned)f2b(r1) << 16);
      r0 = fmaf(gC, r0, b2f((u16)(v & 0xffff)));
      r1 = fmaf(gC, r1, b2f((u16)(v >> 16)));
    }
  }
}

// ---------------- K4: per-chunk output via MFMA (both j-halves in one pass) -------
__global__ __launch_bounds__(256) void retention_out(
    const u16* __restrict__ Qh, const u16* __restrict__ Kh,
    const u16* __restrict__ VT, const u16* __restrict__ Tt,
    float* __restrict__ Out)
{
  __shared__ u16 SM[40960];   // 80KB: Sc 32KB | St0 16KB | St1 16KB | St2 16KB
  const int t = threadIdx.x, l = t & 63, wid = t >> 6;
  const int g = l >> 4, l15 = l & 15;
  const int c = blockIdx.x, b = blockIdx.y;
  u16* Sc  = SM;
  u16* St0 = SM + 16384;
  u16* St1 = SM + 24576;
  u16* St2 = SM + 32768;
  const size_t chunkrow = ((size_t)(b*S_ + c*C_)) << 8;   // * H_

  // ---- phase 1: St[m][n] = sum_d K[m,d] Q[n,d]; mask+decay -> Sc[n][m] (swizzled) ----
  {
    const int m0w = (wid >> 1)*64, n0w = (wid & 1)*64;
    f32x4 acc[4][4] = {};
    for (int ks = 0; ks < 4; ++ks) {
      stageA(Kh + chunkrow + ks*64, H_, SM, 16384, t);   // St0
      stageA(Qh + chunkrow + ks*64, H_, SM, 32768, t);   // St2
      __syncthreads();
      #pragma unroll
      for (int kb = 0; kb < 2; ++kb) {
        short8 a[4], bb[4];
        #pragma unroll
        for (int i = 0; i < 4; ++i) a[i] = fragr(St0, m0w + i*16 + l15, kb*4 + g);
        #pragma unroll
        for (int j = 0; j < 4; ++j) bb[j] = fragr(St2, n0w + j*16 + l15, kb*4 + g);
        #pragma unroll
        for (int i = 0; i < 4; ++i)
          #pragma unroll
          for (int j = 0; j < 4; ++j)
            acc[i][j] = mfma16(a[i], bb[j], acc[i][j]);
      }
      __syncthreads();
    }
    #pragma unroll
    for (int jb = 0; jb < 4; ++jb) {
      const int n = n0w + jb*16 + l15;
      #pragma unroll
      for (int ib = 0; ib < 4; ++ib) {
        const int m0 = m0w + ib*16 + g*4;
        ushort4 pk;
        #pragma unroll
        for (int r = 0; r < 4; ++r) {
          const int m = m0 + r;
          const float sv = (n >= m) ? acc[ib][jb][r] * exp2f((float)(n - m)*L2G) : 0.f;
          reinterpret_cast<u16*>(&pk)[r] = f2b(sv);
        }
        *reinterpret_cast<ushort4*>(Sc + n*128 + (m0 ^ ((n & 15) << 3))) = pk;
      }
    }
  }
  __syncthreads();

  // ---- phase 2: D[j][n] = g^(n+1) (Q@state)^T + (S V)^T, BOTH j-halves at once ----
  const int j0w = (wid >> 1)*64, n0w = (wid & 1)*64;
  const size_t sbase = ((size_t)(b*NC_ + c)) << 16;
  f32x4 accA[4][4] = {};   // j-half 0 (cols 0..127)
  f32x4 accB[4][4] = {};   // j-half 1 (cols 128..255)
  // cross: contraction over d (4 ksteps); A = state rows (per half), B = Q
  for (int ks = 0; ks < 4; ++ks) {
    stageA(Tt + sbase + ks*64, H_, SM, 16384, t);                    // St0: rows 0..127
    stageA(Tt + sbase + (size_t)128*H_ + ks*64, H_, SM, 24576, t);   // St1: rows 128..255
    stageA(Qh + chunkrow + ks*64, H_, SM, 32768, t);                 // St2: Q
    __syncthreads();
    #pragma unroll
    for (int kb = 0; kb < 2; ++kb) {
      short8 a0[4], a1[4], q[4];
      #pragma unroll
      for (int i = 0; i < 4; ++i) {
        a0[i] = fragr(St0, j0w + i*16 + l15, kb*4 + g);
        a1[i] = fragr(St1, j0w + i*16 + l15, kb*4 + g);
      }
      #pragma unroll
      for (int j = 0; j < 4; ++j) q[j] = fragr(St2, n0w + j*16 + l15, kb*4 + g);
      #pragma unroll
      for (int i = 0; i < 4; ++i)
        #pragma unroll
        for (int j = 0; j < 4; ++j) {
          accA[i][j] = mfma16(a0[i], q[j], accA[i][j]);
          accB[i][j] = mfma16(a1[i], q[j], accB[i][j]);
        }
    }
    __syncthreads();
  }
  // scale cross term by gamma^(n+1)
  #pragma unroll
  for (int jb = 0; jb < 4; ++jb) {
    const float gn = exp2f((float)(n0w + jb*16 + l15 + 1) * L2G);
    #pragma unroll
    for (int ib = 0; ib < 4; ++ib)
      #pragma unroll
      for (int r = 0; r < 4; ++r) { accA[ib][jb][r] *= gn; accB[ib][jb][r] *= gn; }
  }
  // local: contraction over m (2 ksteps); A = VT rows (per half), B = Sc
  for (int ks2 = 0; ks2 < 2; ++ks2) {
    stageA(VT + ((size_t)(b*H_)       << 13) + c*C_ + ks2*64, S_, SM, 16384, t);  // St0
    stageA(VT + ((size_t)(b*H_ + 128) << 13) + c*C_ + ks2*64, S_, SM, 24576, t);  // St1
    __syncthreads();
    #pragma unroll
    for (int kb = 0; kb < 2; ++kb) {
      short8 a0[4], a1[4], bb[4];
      #pragma unroll
      for (int i = 0; i < 4; ++i) {
        a0[i] = fragr(St0, j0w + i*16 + l15, kb*4 + g);
        a1[i] = fragr(St1, j0w + i*16 + l15, kb*4 + g);
      }
      #pragma unroll
      for (int j = 0; j < 4; ++j) {
        const int n = n0w + j*16 + l15;
        bb[j] = *reinterpret_cast<const short8*>(
            Sc + n*128 + (((ks2*8 + kb*4 + g) ^ (n & 15)) << 3));
      }
      #pragma unroll
      for (int i = 0; i < 4; ++i)
        #pragma unroll
        for (int j = 0; j < 4; ++j) {
          accA[i][j] = mfma16(a0[i], bb[j], accA[i][j]);
          accB[i][j] = mfma16(a1[i], bb[j], accB[i][j]);
        }
    }
    __syncthreads();
  }
  // epilogue per half: restage [64 n][128 j] f32 in LDS (swizzled), coalesced store
  float* OL = reinterpret_cast<float*>(SM + 16384);   // 32KB = St0+St1 region
  #pragma unroll
  for (int hh = 0; hh < 2; ++hh) {
    const int j0 = hh*128;
    for (int ph = 0; ph < 2; ++ph) {
      if ((wid & 1) == ph) {
        #pragma unroll
        for (int jb = 0; jb < 4; ++jb) {
          const int nl = jb*16 + l15;
          #pragma unroll
          for (int ib = 0; ib < 4; ++ib) {
            const int jl = j0w + ib*16 + g*4;
            *reinterpret_cast<f32x4*>(OL + nl*128 + (jl ^ ((nl & 15) << 2))) =
                hh ? accB[ib][jb] : accA[ib][jb];
          }
        }
      }
      __syncthreads();
      #pragma unroll
      for (int it = 0; it < 8; ++it) {
        const int u = it*256 + t;
        const int nl = u >> 5, sl = u & 31;
        f32x4 v = *reinterpret_cast<const f32x4*>(OL + nl*128 + ((sl ^ (nl & 15)) << 2));
        const int n = c*C_ + ph*64 + nl;
        *reinterpret_cast<f32x4*>(Out + (((size_t)(b*S_ + n)) << 8) + j0 + sl*4) = v;
      }
      __syncthreads();
    }
  }
}

extern "C" void kernel_launch(void* const* d_in, const int* in_sizes, int n_in,
                              void* d_out, int out_size, void* d_ws, size_t ws_size,
                              hipStream_t stream) {
  const float* X  = (const float*)d_in[0];
  const float* Wq = (const float*)d_in[1];
  const float* Wk = (const float*)d_in[2];
  const float* Wv = (const float*)d_in[3];
  float* Out = (float*)d_out;
  u16* ws = (u16*)d_ws;
  // workspace (u16): WhT 196608 | RTab 4194304 | Xh | Qh,Kh,KT,VT,VTw | Tt
  u16*   WhT  = ws;
  float* RTab = (float*)(ws + 196608);
  u16* Xh  = ws  + 196608 + 4194304;
  u16* Qh  = Xh  + (size_t)M_*H_;
  u16* Kh  = Qh  + (size_t)M_*H_;
  u16* KT  = Kh  + (size_t)M_*H_;
  u16* VT  = KT  + (size_t)M_*H_;
  u16* VTw = VT  + (size_t)M_*H_;
  u16* Tt  = VTw + (size_t)M_*H_;

  prep<<<96 + 4096 + 4096, 256, 0, stream>>>(X, Wq, Wk, Wv, Xh, WhT, RTab);
  gemm_qkv<<<dim3(M_/128, H_/128, 3), 256, 0, stream>>>(Xh, WhT, RTab, Qh, Kh, KT, VT, VTw);
  chunk_outer<<<dim3(NC_, B_, 4), 256, 0, stream>>>(KT, VTw, Tt);
  scan_state<<<(B_*32768)/256, 256, 0, stream>>>(Tt);
  retention_out<<<dim3(NC_, B_), 256, 0, stream>>>(Qh, Kh, VT, Tt, Out);
}

// Round 7
// 86.191 us; speedup vs baseline: 1.5809x; 1.3088x over previous
//
#include <hip/hip_runtime.h>
#include <hip/hip_bf16.h>

#define B_  4
#define S_  8192
#define H_  256
#define C_  128
#define NC_ 64
#define M_  (B_*S_)

typedef unsigned short u16;
typedef __attribute__((ext_vector_type(8))) short short8;
typedef __attribute__((ext_vector_type(4))) float f32x4;
typedef __attribute__((address_space(1))) void gas_t;
typedef __attribute__((address_space(3))) void las_t;

static constexpr float L2G   = -0.045803690f;          // log2(0.96875)
static constexpr float ROPE2 = -0.103810253f;          // -(2/256)*log2(10000)

__device__ __forceinline__ u16 f2b(float x) {
  union { __hip_bfloat16 b; u16 u; } c; c.b = __float2bfloat16(x); return c.u;
}
__device__ __forceinline__ float b2f(u16 u) {
  union { u16 u; __hip_bfloat16 b; } c; c.u = u; return __bfloat162float(c.b);
}
__device__ __forceinline__ f32x4 mfma16(short8 a, short8 b, f32x4 c) {
  return __builtin_amdgcn_mfma_f32_16x16x32_bf16(a, b, c, 0, 0, 0);
}

// ---- fragment readers: swizzled rows, 16B-slot phys = keep-high-bits | (low3 ^ row&7) ----
__device__ __forceinline__ short8 fr32(const u16* base, int row, int slot) {   // 256-col rows
  return *reinterpret_cast<const short8*>(base + row*256 + (((slot&24)|((slot&7)^(row&7)))<<3));
}
__device__ __forceinline__ short8 fr16(const u16* base, int row, int slot) {   // 128-col rows
  return *reinterpret_cast<const short8*>(base + row*128 + (((slot&8)|((slot&7)^(row&7)))<<3));
}
__device__ __forceinline__ short8 fr4(const u16* base, int row, int slot) {    // 32-col rows
  return *reinterpret_cast<const short8*>(base + row*32 + ((slot ^ (row&3))<<3));
}
__device__ __forceinline__ short8 fragr(const u16* lds, int row, int slot) {   // 64-col rows (K3)
  return *reinterpret_cast<const short8*>(lds + row*64 + ((slot ^ (row & 7)) << 3));
}

// async [128 rows][64 cols] bf16 tile stage (256-thr), pre-swizzled source (K3)
__device__ __forceinline__ void stageA(const u16* __restrict__ src, int stride,
                                       u16* smbase, int off, int t) {
  #pragma unroll
  for (int it = 0; it < 4; ++it) {
    const int u = it*256 + t, row = u >> 3, lsl = (u & 7) ^ (row & 7);
    const u16* gp = src + (size_t)row*stride + lsl*8;
    u16* lp = smbase + off + it*2048 + (t & 192)*8;
    __builtin_amdgcn_global_load_lds((gas_t*)gp, (las_t*)lp, 16, 0, 0);
  }
}
// async W tile [256 n][32 k] bf16 stage (512-thr), linear LDS dest, inv-swizzled source
__device__ __forceinline__ void stageW(const u16* __restrict__ src, u16* dst, int t) {
  #pragma unroll
  for (int it = 0; it < 2; ++it) {
    const int u = it*512 + t, row = u >> 2, p = u & 3, s = p ^ (row & 3);
    const u16* gp = src + (size_t)row*256 + s*8;
    u16* lp = dst + (size_t)(it*512 + (t & ~63))*8;
    __builtin_amdgcn_global_load_lds((gas_t*)gp, (las_t*)lp, 16, 0, 0);
  }
}

// ---------------- K0: prep — W -> transposed bf16 [z][n][k], RoPE table ----------------
__global__ __launch_bounds__(256) void prep(
    const float* __restrict__ Wq, const float* __restrict__ Wk,
    const float* __restrict__ Wv, u16* __restrict__ WhT, float* __restrict__ RTab)
{
  const int bid = blockIdx.x;
  if (bid < 96) {
    const int i = bid*256 + threadIdx.x;
    const int z = i >> 13, r = i & 8191;
    const int n = r >> 5, k0 = (r & 31) << 3;
    const float* W = (z == 0) ? Wq : (z == 1) ? Wk : Wv;
    u16 o[8];
    #pragma unroll
    for (int j = 0; j < 8; ++j) o[j] = f2b(W[(size_t)(k0 + j)*H_ + n]);
    *reinterpret_cast<uint4*>(WhT + ((size_t)z << 16) + n*H_ + k0) =
        *reinterpret_cast<uint4*>(o);
    return;
  }
  const int i = (bid - 96)*256 + threadIdx.x;    // 0..1048575
  const int s = i >> 7, h = i & 127;
  const float invf = exp2f(ROPE2 * (float)h);
  float sn, cs;
  sincosf((float)s * invf, &sn, &cs);
  *reinterpret_cast<float2*>(RTab + 2*((size_t)s*128 + h)) = make_float2(cs, sn);
}

// ---------------- K1: fused per-(b,chunk): QKV + RoPE + T + Sc + local output ----------
// LDS map (u16 idx): XS [0,32768) = X chunk [128 m][256 d] (later KTw [256 d][128 m], then T restage)
//                    WB [32768,49152) = W dbuf 2x8192 (later K_rm half [128 m][128 dl], then Sc [128 n][128 m])
//                    RB [49152,81920) = Q_rm [128 m][256 n] (later Wv dbuf, then VT [256 j][128 m], then O restage)
__global__ __launch_bounds__(512, 2) void fused_chunk(
    const float* __restrict__ X, const u16* __restrict__ WhT,
    const float* __restrict__ RTab,
    u16* __restrict__ Qh, u16* __restrict__ Tt, float* __restrict__ Oloc)
{
  __shared__ u16 SM[81920];   // 160 KB
  u16* XS = SM;
  u16* WB = SM + 32768;
  u16* RB = SM + 49152;
  const int t = threadIdx.x, l = t & 63, wid = t >> 6;
  const int g = l >> 4, l15 = l & 15;
  const int mr = wid >> 2, nq = wid & 3;        // GEMM wave grid: 2m x 4n
  const int c = blockIdx.x, b = blockIdx.y;
  const float* Xc = X + ((size_t)(b*S_ + c*C_))*H_;
  const float4* RT4 = reinterpret_cast<const float4*>(RTab);

  // ---- T0: issue W(ks=0) async, then reg-stage X chunk f32->bf16 into XS ----
  stageW(WhT + 0, WB, t);
  #pragma unroll
  for (int it = 0; it < 8; ++it) {
    const int u = it*512 + t, row = u >> 5, sl = u & 31;
    const float* p = Xc + (size_t)row*256 + sl*8;
    float4 a = *reinterpret_cast<const float4*>(p);
    float4 bb = *reinterpret_cast<const float4*>(p + 4);
    u16 o[8] = {f2b(a.x), f2b(a.y), f2b(a.z), f2b(a.w),
                f2b(bb.x), f2b(bb.y), f2b(bb.z), f2b(bb.w)};
    *reinterpret_cast<uint4*>(XS + row*256 + (((sl&24)|((sl&7)^(row&7)))<<3)) =
        *reinterpret_cast<uint4*>(o);
  }
  __syncthreads();

  // ---- T1: Q-GEMM (swapped: l15=m, regs=consec n) ----
  f32x4 qa[4][4] = {};
  for (int ks = 0; ks < 8; ++ks) {
    const u16* Wcur = WB + (ks&1)*8192;
    if (ks < 7) stageW(WhT + (ks+1)*32, WB + ((ks+1)&1)*8192, t);
    short8 a[4], bw[4];
    #pragma unroll
    for (int i = 0; i < 4; ++i) a[i] = fr32(XS, mr*64 + i*16 + l15, ks*4 + g);
    #pragma unroll
    for (int j = 0; j < 4; ++j) bw[j] = fr4(Wcur, nq*64 + j*16 + l15, g);
    #pragma unroll
    for (int i = 0; i < 4; ++i)
      #pragma unroll
      for (int j = 0; j < 4; ++j)
        qa[i][j] = mfma16(bw[j], a[i], qa[i][j]);
    __syncthreads();
  }
  // rope Q
  #pragma unroll
  for (int i = 0; i < 4; ++i) {
    const int s = c*C_ + mr*64 + i*16 + l15;
    #pragma unroll
    for (int j = 0; j < 4; ++j) {
      const int n0 = nq*64 + j*16 + g*4;
      const float4 tb = RT4[(size_t)s*64 + (n0 >> 2)];
      const float x0 = qa[i][j][0], x1 = qa[i][j][1];
      const float x2 = qa[i][j][2], x3 = qa[i][j][3];
      qa[i][j][0] = x0*tb.x - x1*tb.y;  qa[i][j][1] = x1*tb.x + x0*tb.y;
      qa[i][j][2] = x2*tb.z - x3*tb.w;  qa[i][j][3] = x3*tb.z + x2*tb.w;
    }
  }
  // restage Q_rm [128 m][256 n] into RB
  #pragma unroll
  for (int i = 0; i < 4; ++i) {
    const int m = mr*64 + i*16 + l15;
    #pragma unroll
    for (int j = 0; j < 4; ++j) {
      const int n0 = nq*64 + j*16 + g*4;
      ushort4 pk;
      pk.x = f2b(qa[i][j][0]); pk.y = f2b(qa[i][j][1]);
      pk.z = f2b(qa[i][j][2]); pk.w = f2b(qa[i][j][3]);
      const int sl = n0 >> 3;
      *reinterpret_cast<ushort4*>(RB + m*256 + (((sl&24)|((sl&7)^(m&7)))<<3) + (n0&7)) = pk;
    }
  }
  __syncthreads();
  // coalesced Qh store
  #pragma unroll
  for (int it = 0; it < 8; ++it) {
    const int u = it*512 + t, row = u >> 5, sl = u & 31;
    uint4 v = *reinterpret_cast<const uint4*>(RB + row*256 + (((sl&24)|((sl&7)^(row&7)))<<3));
    *reinterpret_cast<uint4*>(Qh + ((size_t)(b*S_ + c*C_ + row))*H_ + sl*8) = v;
  }

  // ---- T4: K-GEMM (swapped) + rope; acc stays in regs ----
  f32x4 ka[4][4] = {};
  stageW(WhT + 65536, WB, t);
  __syncthreads();
  for (int ks = 0; ks < 8; ++ks) {
    const u16* Wcur = WB + (ks&1)*8192;
    if (ks < 7) stageW(WhT + 65536 + (ks+1)*32, WB + ((ks+1)&1)*8192, t);
    short8 a[4], bw[4];
    #pragma unroll
    for (int i = 0; i < 4; ++i) a[i] = fr32(XS, mr*64 + i*16 + l15, ks*4 + g);
    #pragma unroll
    for (int j = 0; j < 4; ++j) bw[j] = fr4(Wcur, nq*64 + j*16 + l15, g);
    #pragma unroll
    for (int i = 0; i < 4; ++i)
      #pragma unroll
      for (int j = 0; j < 4; ++j)
        ka[i][j] = mfma16(bw[j], a[i], ka[i][j]);
    __syncthreads();
  }
  #pragma unroll
  for (int i = 0; i < 4; ++i) {
    const int s = c*C_ + mr*64 + i*16 + l15;
    #pragma unroll
    for (int j = 0; j < 4; ++j) {
      const int n0 = nq*64 + j*16 + g*4;
      const float4 tb = RT4[(size_t)s*64 + (n0 >> 2)];
      const float x0 = ka[i][j][0], x1 = ka[i][j][1];
      const float x2 = ka[i][j][2], x3 = ka[i][j][3];
      ka[i][j][0] = x0*tb.x - x1*tb.y;  ka[i][j][1] = x1*tb.x + x0*tb.y;
      ka[i][j][2] = x2*tb.z - x3*tb.w;  ka[i][j][3] = x3*tb.z + x2*tb.w;
    }
  }

  // ---- T5: Sc-GEMM in two d-halves; K_rm half staged via WB ----
  const int smh = wid >> 2, sn0 = (wid & 3)*32;   // Sc wave grid: 2m x 4n(32)
  f32x4 sc[4][2] = {};
  #pragma unroll
  for (int h = 0; h < 2; ++h) {
    if (((wid >> 1) & 1) == h) {   // waves nq in {2h, 2h+1} hold this d-half
      #pragma unroll
      for (int i = 0; i < 4; ++i) {
        const int m = mr*64 + i*16 + l15;
        #pragma unroll
        for (int j = 0; j < 4; ++j) {
          const int dl0 = (nq&1)*64 + j*16 + g*4;
          ushort4 pk;
          pk.x = f2b(ka[i][j][0]); pk.y = f2b(ka[i][j][1]);
          pk.z = f2b(ka[i][j][2]); pk.w = f2b(ka[i][j][3]);
          const int sl = dl0 >> 3;
          *reinterpret_cast<ushort4*>(WB + m*128 + (((sl&8)|((sl&7)^(m&7)))<<3) + (dl0&7)) = pk;
        }
      }
    }
    __syncthreads();
    #pragma unroll
    for (int kk = 0; kk < 4; ++kk) {
      short8 fa[4], fb[2];
      #pragma unroll
      for (int i = 0; i < 4; ++i) fa[i] = fr16(WB, smh*64 + i*16 + l15, kk*4 + g);
      #pragma unroll
      for (int j = 0; j < 2; ++j) fb[j] = fr32(RB, sn0 + j*16 + l15, h*16 + kk*4 + g);
      #pragma unroll
      for (int i = 0; i < 4; ++i)
        #pragma unroll
        for (int j = 0; j < 2; ++j)
          sc[i][j] = mfma16(fa[i], fb[j], sc[i][j]);
    }
    __syncthreads();
  }
  // mask + decay -> Sc [128 n][128 m] bf16 into WB
  #pragma unroll
  for (int j = 0; j < 2; ++j) {
    const int n = sn0 + j*16 + l15;
    #pragma unroll
    for (int i = 0; i < 4; ++i) {
      const int m0 = smh*64 + i*16 + g*4;
      ushort4 pk;
      #pragma unroll
      for (int r = 0; r < 4; ++r) {
        const int m = m0 + r;
        const float sv = (n >= m) ? sc[i][j][r] * exp2f((float)(n - m)*L2G) : 0.f;
        reinterpret_cast<u16*>(&pk)[r] = f2b(sv);
      }
      const int sl = m0 >> 3;
      *reinterpret_cast<ushort4*>(WB + n*128 + (((sl&8)|((sl&7)^(n&7)))<<3) + (m0&7)) = pk;
    }
  }
  __syncthreads();

  // ---- T7: V-GEMM (normal: l15=n(j), regs=consec m); Wv streams via RB front ----
  f32x4 va[4][4] = {};
  stageW(WhT + 2*65536, RB, t);
  __syncthreads();
  for (int ks = 0; ks < 8; ++ks) {
    const u16* Wcur = RB + (ks&1)*8192;
    if (ks < 7) stageW(WhT + 2*65536 + (ks+1)*32, RB + ((ks+1)&1)*8192, t);
    short8 a[4], bw[4];
    #pragma unroll
    for (int i = 0; i < 4; ++i) a[i] = fr32(XS, mr*64 + i*16 + l15, ks*4 + g);
    #pragma unroll
    for (int j = 0; j < 4; ++j) bw[j] = fr4(Wcur, nq*64 + j*16 + l15, g);
    #pragma unroll
    for (int i = 0; i < 4; ++i)
      #pragma unroll
      for (int j = 0; j < 4; ++j)
        va[i][j] = mfma16(a[i], bw[j], va[i][j]);
    __syncthreads();
  }

  // ---- T8: VT [256 j][128 m] -> RB; KTw [256 d][128 m] (decay-weighted K) -> XS ----
  #pragma unroll
  for (int jj = 0; jj < 4; ++jj) {
    const int j = nq*64 + jj*16 + l15;
    #pragma unroll
    for (int i = 0; i < 4; ++i) {
      const int m0 = mr*64 + i*16 + g*4;
      ushort4 pk;
      pk.x = f2b(va[i][jj][0]); pk.y = f2b(va[i][jj][1]);
      pk.z = f2b(va[i][jj][2]); pk.w = f2b(va[i][jj][3]);
      const int sl = m0 >> 3;
      *reinterpret_cast<ushort4*>(RB + j*128 + (((sl&8)|((sl&7)^(j&7)))<<3) + (m0&7)) = pk;
    }
  }
  #pragma unroll
  for (int i = 0; i < 4; ++i) {
    const int m = mr*64 + i*16 + l15;
    const float w = exp2f((float)(C_ - 1 - m)*L2G);
    const int slm = m >> 3;
    #pragma unroll
    for (int jj = 0; jj < 4; ++jj) {
      #pragma unroll
      for (int r = 0; r < 4; ++r) {
        const int d = nq*64 + jj*16 + g*4 + r;
        XS[d*128 + (((slm&8)|((slm&7)^(d&7)))<<3) + (m&7)] = f2b(ka[i][jj][r] * w);
      }
    }
  }
  __syncthreads();

  // ---- T9: T-GEMM  T[j][i] = sum_m VT[j,m]*KTw[i,m]  (l15=j, regs=consec i) ----
  const int ih = wid & 1, jq = wid >> 1;
  {
    f32x4 tt[8][4] = {};
    #pragma unroll
    for (int kk = 0; kk < 4; ++kk) {
      short8 fk[8], fv[4];
      #pragma unroll
      for (int ii = 0; ii < 8; ++ii) fk[ii] = fr16(XS, ih*128 + ii*16 + l15, kk*4 + g);
      #pragma unroll
      for (int jj = 0; jj < 4; ++jj) fv[jj] = fr16(RB, jq*64 + jj*16 + l15, kk*4 + g);
      #pragma unroll
      for (int ii = 0; ii < 8; ++ii)
        #pragma unroll
        for (int jj = 0; jj < 4; ++jj)
          tt[ii][jj] = mfma16(fk[ii], fv[jj], tt[ii][jj]);
    }
    __syncthreads();   // all KTw reads done before XS reuse
    const size_t tb = ((size_t)(b*NC_ + c)) << 16;
    #pragma unroll
    for (int p = 0; p < 2; ++p) {
      if ((jq >> 1) == p) {
        #pragma unroll
        for (int ii = 0; ii < 8; ++ii)
          #pragma unroll
          for (int jj = 0; jj < 4; ++jj) {
            const int jl = (jq&1)*64 + jj*16 + l15;
            const int i0 = ih*128 + ii*16 + g*4;
            ushort4 pk;
            pk.x = f2b(tt[ii][jj][0]); pk.y = f2b(tt[ii][jj][1]);
            pk.z = f2b(tt[ii][jj][2]); pk.w = f2b(tt[ii][jj][3]);
            const int sl = i0 >> 3;
            *reinterpret_cast<ushort4*>(XS + jl*256 + (((sl&24)|((sl&7)^(jl&7)))<<3) + (i0&7)) = pk;
          }
      }
      __syncthreads();
      #pragma unroll
      for (int it = 0; it < 8; ++it) {
        const int u = it*512 + t, row = u >> 5, sl = u & 31;
        uint4 v = *reinterpret_cast<const uint4*>(XS + row*256 + (((sl&24)|((sl&7)^(row&7)))<<3));
        *reinterpret_cast<uint4*>(Tt + tb + (size_t)(p*128 + row)*256 + sl*8) = v;
      }
      __syncthreads();
    }
  }

  // ---- T10: O-GEMM  out[j][n] = sum_m VT[j,m]*Sc[n,m]  (l15=n, regs=consec j) ----
  {
    f32x4 oa[4][4] = {};
    const int ojq = wid >> 1, onh = wid & 1;
    #pragma unroll
    for (int kk = 0; kk < 4; ++kk) {
      short8 fv[4], fs[4];
      #pragma unroll
      for (int jj = 0; jj < 4; ++jj) fv[jj] = fr16(RB, ojq*64 + jj*16 + l15, kk*4 + g);
      #pragma unroll
      for (int nn = 0; nn < 4; ++nn) fs[nn] = fr16(WB, onh*64 + nn*16 + l15, kk*4 + g);
      #pragma unroll
      for (int jj = 0; jj < 4; ++jj)
        #pragma unroll
        for (int nn = 0; nn < 4; ++nn)
          oa[jj][nn] = mfma16(fv[jj], fs[nn], oa[jj][nn]);
    }
    __syncthreads();   // VT reads done before RB reuse
    float* RBf = reinterpret_cast<float*>(RB);
    #pragma unroll
    for (int p = 0; p < 2; ++p) {
      if (onh == p) {
        #pragma unroll
        for (int jj = 0; jj < 4; ++jj)
          #pragma unroll
          for (int nn = 0; nn < 4; ++nn) {
            const int nl = nn*16 + l15;
            const int j0 = ojq*64 + jj*16 + g*4;
            const int sl = j0 >> 2;
            *reinterpret_cast<f32x4*>(RBf + nl*256 + (((sl&56)|((sl&7)^(nl&7)))<<2)) = oa[jj][nn];
          }
      }
      __syncthreads();
      #pragma unroll
      for (int it = 0; it < 8; ++it) {
        const int u = it*512 + t, nl = u >> 6, sl = u & 63;
        f32x4 v = *reinterpret_cast<const f32x4*>(RBf + nl*256 + (((sl&56)|((sl&7)^(nl&7)))<<2));
        *reinterpret_cast<f32x4*>(Oloc + ((size_t)(b*S_ + c*C_ + p*64 + nl))*256 + sl*4) = v;
      }
      __syncthreads();
    }
  }
}

// ---------------- K2: exclusive scan: state[c] = g^C state[c-1] + T[c-1] ----------------
__global__ __launch_bounds__(256) void scan_state(u16* __restrict__ Tt)
{
  const unsigned e = blockIdx.x*256u + threadIdx.x;   // B_*32768 threads, 2 elems each
  const unsigned b = e >> 15, el = (e & 32767u) << 1;
  const float gC = exp2f(128.0f * L2G);
  float r0 = 0.f, r1 = 0.f;
  const size_t base = (((size_t)b * NC_) << 16) + el;
  #pragma unroll
  for (int grp = 0; grp < 4; ++grp) {
    unsigned buf[16];
    #pragma unroll
    for (int i2 = 0; i2 < 16; ++i2)
      buf[i2] = *reinterpret_cast<const unsigned*>(Tt + base + (size_t)(grp*16 + i2)*65536);
    #pragma unroll
    for (int i2 = 0; i2 < 16; ++i2) {
      const unsigned v = buf[i2];
      *reinterpret_cast<unsigned*>(Tt + base + (size_t)(grp*16 + i2)*65536) =
          (unsigned)f2b(r0) | ((unsigned)f2b(r1) << 16);
      r0 = fmaf(gC, r0, b2f((u16)(v & 0xffff)));
      r1 = fmaf(gC, r1, b2f((u16)(v >> 16)));
    }
  }
}

// ---------------- K3: cross term: Out = Oloc + g^(n+1) * (Q @ state) ----------------
__global__ __launch_bounds__(256) void cross_out(
    const u16* __restrict__ Qh, const u16* __restrict__ Tt,
    const float* __restrict__ Oloc, float* __restrict__ Out)
{
  __shared__ u16 SM[32768];   // 64KB: dbuf {A0,B0,A1,B1}x16KB; epilogue reuses [0,16384)
  const int t = threadIdx.x, l = t & 63, wid = t >> 6;
  const int wr = wid >> 1, wc = wid & 1, g = l >> 4, l15 = l & 15;
  const int c = blockIdx.x, b = blockIdx.y, jh = blockIdx.z;
  const u16* Asrc = Qh + (size_t)(b*S_ + c*C_)*H_;
  const u16* Bsrc = Tt + (((size_t)(b*NC_ + c)) << 16) + (size_t)(jh*128)*H_;
  f32x4 acc[4][4] = {};

  stageA(Asrc, H_, SM, 0, t);
  stageA(Bsrc, H_, SM, 8192, t);
  __syncthreads();
  for (int ks = 0; ks < 4; ++ks) {
    const int cur = (ks & 1) * 16384;
    if (ks < 3) {
      stageA(Asrc + (ks+1)*64, H_, SM, 16384 - cur, t);
      stageA(Bsrc + (ks+1)*64, H_, SM, 16384 - cur + 8192, t);
    }
    #pragma unroll
    for (int kb = 0; kb < 2; ++kb) {
      short8 fq[4], ft[4];
      #pragma unroll
      for (int i = 0; i < 4; ++i) fq[i] = fragr(SM + cur, wr*64 + i*16 + l15, kb*4 + g);
      #pragma unroll
      for (int j = 0; j < 4; ++j) ft[j] = fragr(SM + cur + 8192, wc*64 + j*16 + l15, kb*4 + g);
      #pragma unroll
      for (int i = 0; i < 4; ++i)
        #pragma unroll
        for (int j = 0; j < 4; ++j)
          acc[i][j] = mfma16(ft[j], fq[i], acc[i][j]);   // l15=n, regs=consec j
    }
    __syncthreads();
  }
  // scale by gamma^(n_local+1)
  #pragma unroll
  for (int i = 0; i < 4; ++i) {
    const float gn = exp2f((float)(wr*64 + i*16 + l15 + 1) * L2G);
    #pragma unroll
    for (int j = 0; j < 4; ++j)
      #pragma unroll
      for (int r = 0; r < 4; ++r) acc[i][j][r] *= gn;
  }
  // restage [64 n][128 j] f32, coalesced read Oloc + add + store Out
  float* OL = reinterpret_cast<float*>(SM);
  for (int ph = 0; ph < 2; ++ph) {
    if (wr == ph) {
      #pragma unroll
      for (int i = 0; i < 4; ++i) {
        const int nl = i*16 + l15;
        #pragma unroll
        for (int j = 0; j < 4; ++j) {
          const int j0 = wc*64 + j*16 + g*4;
          const int sl = j0 >> 2;
          *reinterpret_cast<f32x4*>(OL + nl*128 + (((sl&24)|((sl&7)^(nl&7)))<<2)) = acc[i][j];
        }
      }
    }
    __syncthreads();
    #pragma unroll
    for (int it = 0; it < 8; ++it) {
      const int u = it*256 + t, nl = u >> 5, sl = u & 31;
      f32x4 v = *reinterpret_cast<const f32x4*>(OL + nl*128 + (((sl&24)|((sl&7)^(nl&7)))<<2));
      const size_t off = ((size_t)(b*S_ + c*C_ + ph*64 + nl))*256 + jh*128 + sl*4;
      f32x4 o = *reinterpret_cast<const f32x4*>(Oloc + off);
      v += o;
      *reinterpret_cast<f32x4*>(Out + off) = v;
    }
    __syncthreads();
  }
}

extern "C" void kernel_launch(void* const* d_in, const int* in_sizes, int n_in,
                              void* d_out, int out_size, void* d_ws, size_t ws_size,
                              hipStream_t stream) {
  const float* X  = (const float*)d_in[0];
  const float* Wq = (const float*)d_in[1];
  const float* Wk = (const float*)d_in[2];
  const float* Wv = (const float*)d_in[3];
  float* Out = (float*)d_out;
  u16* ws = (u16*)d_ws;
  // workspace (u16 units): WhT 196608 | RTab 4194304 | Qh 8388608 | Tt 16777216 | Oloc(f32) 16777216
  u16*   WhT  = ws;
  float* RTab = (float*)(ws + 196608);
  u16*   Qh   = ws + 196608 + 4194304;
  u16*   Tt   = Qh + (size_t)M_*H_;
  float* Oloc = (float*)(Tt + (size_t)B_*NC_*65536);

  prep<<<96 + 4096, 256, 0, stream>>>(Wq, Wk, Wv, WhT, RTab);
  fused_chunk<<<dim3(NC_, B_), 512, 0, stream>>>(X, WhT, RTab, Qh, Tt, Oloc);
  scan_state<<<(B_*32768)/256, 256, 0, stream>>>(Tt);
  cross_out<<<dim3(NC_, B_, 2), 256, 0, stream>>>(Qh, Tt, Oloc, Out);
}